// Round 9
// baseline (88.906 us; speedup 1.0000x reference)
//
#include <hip/hip_runtime.h>
#include <hip/hip_bf16.h>
#include <hip/hip_fp16.h>
#include <math.h>

#define LRELU_ALPHA 0.2f

typedef __attribute__((ext_vector_type(8))) short bf16x8;
typedef __attribute__((ext_vector_type(4))) float f32x4;

__device__ __forceinline__ unsigned short f2bf(float f) {
    union { float f; unsigned u; } v; v.f = f;
    unsigned r = v.u + 0x7fffu + ((v.u >> 16) & 1u);
    return (unsigned short)(r >> 16);
}
__device__ __forceinline__ unsigned cvtpk(float lo, float hi) {
    unsigned r;
    asm("v_cvt_pk_bf16_f32 %0, %1, %2" : "=v"(r) : "v"(lo), "v"(hi));
    return r;
}
// async gather into LDS: per-lane GLOBAL address, linear LDS dest (base+lane*16)
__device__ __forceinline__ void gload_lds16(const void* g, void* l) {
    __builtin_amdgcn_global_load_lds(
        (const __attribute__((address_space(1))) void*)g,
        (__attribute__((address_space(3))) void*)l, 16, 0, 0);
}
#define VMWAIT0() do { asm volatile("s_waitcnt vmcnt(0)" ::: "memory"); \
                       __builtin_amdgcn_sched_barrier(0); } while (0)

// ---------------- prep: Wt transpose + score-row projection + edge_out ----------------
// Wt[h][n][k] = bf16(W[h][k][n]) for n<64; n=64+q (q<4): bf16(sum_o W[h][k][o]*a_q[o]);
// q>=4 zeroed (deterministic). Tail: edge_out = ee @ et (lane=o coalesced).
__global__ void prep_kernel(const float* __restrict__ W,
                            const float* __restrict__ a_pos, const float* __restrict__ a_neg,
                            const float* __restrict__ ee, const float* __restrict__ et,
                            unsigned short* __restrict__ Wt, float* __restrict__ edge_out,
                            int H, int ET) {
    const int HE = H * 64 * 64;
    const int AV = H * 16 * 64;
    int t = blockIdx.x * blockDim.x + threadIdx.x;
    if (t < HE) {
        int k = t & 63, n = (t >> 6) & 63, h = t >> 12;
        Wt[((size_t)h * 80 + n) * 64 + k] = f2bf(W[(size_t)h * 4096 + k * 64 + n]);
    } else if (t < HE + AV) {
        int s = t - HE;
        int k = s & 63, q = (s >> 6) & 15, h = s >> 10;
        float v = 0.f;
        if (q < 4) {
            const float* a  = (q < 2 ? a_pos : a_neg) + (size_t)h * 128 + (q & 1) * 64;
            const float* wr = W + (size_t)h * 4096 + k * 64;
#pragma unroll
            for (int o = 0; o < 64; o += 4) {
                const float4 wv = *(const float4*)(wr + o);
                const float4 av = *(const float4*)(a + o);
                v = fmaf(wv.x, av.x, fmaf(wv.y, av.y, fmaf(wv.z, av.z, fmaf(wv.w, av.w, v))));
            }
        }
        Wt[((size_t)h * 80 + 64 + q) * 64 + k] = f2bf(v);
    } else {
        int s = t - HE - AV;
        if (s < ET * 64) {
            int e = s >> 6, o = s & 63;
            float acc = 0.f;
#pragma unroll
            for (int k = 0; k < 64; ++k)
                acc = fmaf(ee[e * 64 + k], et[k * 64 + o], acc);
            edge_out[s] = acc;
        }
    }
}

// ---------------- wh: swapped-operand MFMA per-wave body (one head, 16 u's) -----------
// Lane (grp,r): dims {nt*16+grp*4+j} of row u=u0+r; WhB row f16 PERMUTED
// (storage pos p = grp*16 + nt*4 + j) -> two coalesced dwordx4 stores.
// sc4[h][u] = {pd, nd, ps, ns}.
__device__ __forceinline__ void wh_body(
    const float* __restrict__ nf, const unsigned short* __restrict__ Wt,
    const int* __restrict__ un, unsigned short* __restrict__ WhB,
    float4* __restrict__ sc4, int U, int h, long u0, int lane)
{
    const int grp = lane >> 4;
    const int r   = lane & 15;
    const long u  = u0 + r;
    const long ur = (u < U) ? u : (long)(U - 1);
    const float* erow = nf + (size_t)un[ur] * 64 + grp * 8;
    const float4 e0 = *(const float4*)(erow);
    const float4 e1 = *(const float4*)(erow + 4);
    const float4 e2 = *(const float4*)(erow + 32);
    const float4 e3 = *(const float4*)(erow + 36);
    union { unsigned d[4]; bf16x8 v; } A0, A1;
    A0.d[0] = cvtpk(e0.x, e0.y); A0.d[1] = cvtpk(e0.z, e0.w);
    A0.d[2] = cvtpk(e1.x, e1.y); A0.d[3] = cvtpk(e1.z, e1.w);
    A1.d[0] = cvtpk(e2.x, e2.y); A1.d[1] = cvtpk(e2.z, e2.w);
    A1.d[2] = cvtpk(e3.x, e3.y); A1.d[3] = cvtpk(e3.z, e3.w);

    f32x4 acc[5];
#pragma unroll
    for (int nt = 0; nt < 5; ++nt) {
        acc[nt] = (f32x4)(0.f);
        const unsigned short* wp = Wt + (((size_t)h * 80 + nt * 16 + r) * 64 + grp * 8);
        bf16x8 b0 = *(const bf16x8*)wp;        // same lane->k map as A frags
        bf16x8 b1 = *(const bf16x8*)(wp + 32);
        acc[nt] = __builtin_amdgcn_mfma_f32_16x16x32_bf16(b0, A0.v, acc[nt], 0, 0, 0);
        acc[nt] = __builtin_amdgcn_mfma_f32_16x16x32_bf16(b1, A1.v, acc[nt], 0, 0, 0);
    }
    if (u < U) {
        union { __half2 h2[4]; uint4 v; } P0, P1;
        P0.h2[0] = __floats2half2_rn(acc[0][0], acc[0][1]);
        P0.h2[1] = __floats2half2_rn(acc[0][2], acc[0][3]);
        P0.h2[2] = __floats2half2_rn(acc[1][0], acc[1][1]);
        P0.h2[3] = __floats2half2_rn(acc[1][2], acc[1][3]);
        P1.h2[0] = __floats2half2_rn(acc[2][0], acc[2][1]);
        P1.h2[1] = __floats2half2_rn(acc[2][2], acc[2][3]);
        P1.h2[2] = __floats2half2_rn(acc[3][0], acc[3][1]);
        P1.h2[3] = __floats2half2_rn(acc[3][2], acc[3][3]);
        unsigned short* wrow = WhB + ((size_t)h * U + u) * 64 + grp * 16;
        *(uint4*)(wrow)     = P0.v;
        *(uint4*)(wrow + 8) = P1.v;
        if (grp == 0)   // q order {pd, ps, nd, ns} -> pack {pd, nd, ps, ns}
            sc4[(size_t)h * U + u] = make_float4(acc[4][0], acc[4][2],
                                                 acc[4][1], acc[4][3]);
    }
}

// Pinned wh (H==4): one head per block, head h on XCD pair {2h,2h+1} so WhB/sc4
// writes land in the L2s agg will read them from. Block = 64 u's (4 waves x 16).
__global__ __launch_bounds__(256) void wh_pinned_kernel(
    const float* __restrict__ nf, const unsigned short* __restrict__ Wt,
    const int* __restrict__ un, unsigned short* __restrict__ WhB,
    float4* __restrict__ sc4, int U)
{
    const int wave = threadIdx.x >> 6;
    const int lane = threadIdx.x & 63;
    const int xcd  = blockIdx.x & 7;
    const int h    = xcd >> 1;
    const int ublk = ((blockIdx.x >> 3) << 1) | (blockIdx.x & 1);
    const long u0  = (long)ublk * 64 + wave * 16;
    if (u0 >= U) return;
    wh_body(nf, Wt, un, WhB, sc4, U, h, u0, lane);
}

// Generic wh: block = 16 u's, wave w handles heads w, w+4, ...
__global__ __launch_bounds__(256) void wh_generic_kernel(
    const float* __restrict__ nf, const unsigned short* __restrict__ Wt,
    const int* __restrict__ un, unsigned short* __restrict__ WhB,
    float4* __restrict__ sc4, int U, int H)
{
    const int wave = threadIdx.x >> 6;
    const int lane = threadIdx.x & 63;
    const long u0  = (long)blockIdx.x * 16;
    if (u0 >= U) return;
    for (int h = wave; h < H; h += 4)
        wh_body(nf, Wt, un, WhB, sc4, U, h, u0, lane);
}

// ---------------- agg fast path: LDS-DMA gather, latency-immune ----------------------
// One (row,head) per wave; head pinned to XCD pair {2h,2h+1}.
// 5x global_load_lds (each: 8 edge-rows, per-lane global addr, 16B/lane) with the
// in-flight state in the DMA queue (register allocator can't serialize it).
// Rule-21 swizzle: source chunk c^g pre-swizzled, same XOR on the ds_read -> the
// readback (lane=dim-chunk, 8 edge groups) is bank-conflict-free.
__global__ __launch_bounds__(256) void agg_pinned_kernel(
    const int* __restrict__ pos_col, const int* __restrict__ neg_col,
    const unsigned short* __restrict__ WhB, const float4* __restrict__ sc4,
    float* __restrict__ out, int N, int U, int H)
{
    constexpr int DP = 16, DN = 16, NE = 33;
    __shared__ __align__(16) unsigned char smem[4 * 5 * 1024];

    const int wave = threadIdx.x >> 6;
    const int lane = threadIdx.x & 63;
    const int xcd  = blockIdx.x & 7;
    const int h    = xcd >> 1;
    const int rg   = ((blockIdx.x >> 3) << 1) | (blockIdx.x & 1);
    const int i    = rg * 4 + wave;

    // stage A: edge cols (pads -> row 0: valid data, att will be 0)
    const int* cp;
    if (lane < DP)       cp = pos_col + (size_t)i * DP + lane;
    else if (lane == DP) cp = pos_col + (size_t)N * DP + i;   // self edge
    else if (lane < NE)  cp = neg_col + (size_t)i * DN + (lane - DP - 1);
    else                 cp = pos_col;
    int col = *cp;
    if (lane >= NE) col = 0;

    // stage B: score vector (issued before the DMAs so its wait leaves them in flight)
    const float4 s4 = sc4[(size_t)h * U + (unsigned)col];
    __builtin_amdgcn_sched_barrier(0);

    // stage C: issue 5 LDS-DMA gathers (40 edge slots)
    const char* whbase = (const char*)WhB + (size_t)h * U * 128;
    unsigned char* lbase = smem + wave * 5120;
    const int g  = lane >> 3;          // edge group within an instruction
    const int c  = lane & 7;           // 16B chunk within a row
    const int cw = c ^ g;              // pre-swizzled source chunk (rule 21)
#pragma unroll
    for (int t = 0; t < 5; ++t) {
        const int e  = 8 * t + g;
        const int ce = __shfl(col, e, 64);
        gload_lds16(whbase + (((size_t)(unsigned)ce) << 7) + (cw << 4),
                    lbase + t * 1024);
    }
    __builtin_amdgcn_sched_barrier(0);  // DMAs may not sink below this point

    // stage D: joint softmax (runs while DMAs fly). Self-edge col == row_unique[i],
    // so dst scores come from lane DP's float4.
    const float sdp = __shfl(s4.x, DP, 64), sdn = __shfl(s4.y, DP, 64);
    float score = -INFINITY;
    if (lane < NE) {
        const float raw = (lane <= DP) ? sdp + s4.z : sdn + s4.w;
        score = (raw > 0.f) ? raw : LRELU_ALPHA * raw;
    }
    float m = score;
#pragma unroll
    for (int off = 32; off; off >>= 1) m = fmaxf(m, __shfl_xor(m, off, 64));
    const float ex = (lane < NE) ? __expf(score - m) : 0.f;
    float ssum = ex;
#pragma unroll
    for (int off = 32; off; off >>= 1) ssum += __shfl_xor(ssum, off, 64);
    const float att = ex / ssum;        // 0 on pad lanes

    __half2 ah[5];
#pragma unroll
    for (int t = 0; t < 5; ++t)
        ah[t] = __float2half2_rn(__shfl(att, 8 * t + g, 64));

    VMWAIT0();   // gathers landed in LDS

    // stage E: conflict-free ds_read_b128 + packed f16 MACs
    __half2 a0 = __float2half2_rn(0.f), a1 = a0, a2 = a0, a3 = a0;
#pragma unroll
    for (int t = 0; t < 5; ++t) {
        union { uint4 u; __half2 hh[4]; } v;
        v.u = *(const uint4*)(lbase + t * 1024 + (g << 7) + ((c ^ g) << 4));
        a0 = __hfma2(ah[t], v.hh[0], a0);
        a1 = __hfma2(ah[t], v.hh[1], a1);
        a2 = __hfma2(ah[t], v.hh[2], a2);
        a3 = __hfma2(ah[t], v.hh[3], a3);
    }
    // f32 tree reduce across the 8 edge groups
    float f0, f1, f2, f3, f4, f5, f6, f7;
    { float2 x = __half22float2(a0); f0 = x.x; f1 = x.y; }
    { float2 x = __half22float2(a1); f2 = x.x; f3 = x.y; }
    { float2 x = __half22float2(a2); f4 = x.x; f5 = x.y; }
    { float2 x = __half22float2(a3); f6 = x.x; f7 = x.y; }
#pragma unroll
    for (int off = 8; off <= 32; off <<= 1) {
        f0 += __shfl_xor(f0, off, 64); f1 += __shfl_xor(f1, off, 64);
        f2 += __shfl_xor(f2, off, 64); f3 += __shfl_xor(f3, off, 64);
        f4 += __shfl_xor(f4, off, 64); f5 += __shfl_xor(f5, off, 64);
        f6 += __shfl_xor(f6, off, 64); f7 += __shfl_xor(f7, off, 64);
    }
    if (lane < 16) {
        const int cc = lane & 7, half = lane >> 3;
        // storage pos p = cc*8 + (half*4 + jj)  ->  dim (cc&1)*32 + half*16 + (cc>>1)*4 + jj
        const int base = (cc & 1) * 32 + half * 16 + (cc >> 1) * 4;
        float4 o;
        if (half == 0) { o.x = f0; o.y = f1; o.z = f2; o.w = f3; }
        else           { o.x = f4; o.y = f5; o.z = f6; o.w = f7; }
        o.x = fmaxf(o.x, 0.f); o.y = fmaxf(o.y, 0.f);
        o.z = fmaxf(o.z, 0.f); o.w = fmaxf(o.w, 0.f);
        *(float4*)(out + (size_t)i * (H * 64) + h * 64 + base) = o;
    }
}

// Generic fallback (any DEG/H): one row-head per wave.
__global__ __launch_bounds__(256) void agg_generic_kernel(
    const int* __restrict__ pos_col, const int* __restrict__ neg_col,
    const unsigned short* __restrict__ WhB, const float4* __restrict__ sc4,
    float* __restrict__ out, int N, int U, int DEGP, int DEGN, int H)
{
    const int wave = threadIdx.x >> 6;
    const int lane = threadIdx.x & 63;
    const long j = (long)blockIdx.x * 4 + wave;
    const int i = (int)(j % N);
    const int h = (int)(j / N);
    if (h >= H) return;
    const int NE = DEGP + 1 + DEGN;

    int col = 0;
    if (lane < DEGP)       col = pos_col[(size_t)i * DEGP + lane];
    else if (lane == DEGP) col = pos_col[(size_t)N * DEGP + i];
    else if (lane < NE)    col = neg_col[(size_t)i * DEGN + (lane - DEGP - 1)];
    const float4 s4 = sc4[(size_t)h * U + col];
    const float sdp = __shfl(s4.x, DEGP, 64), sdn = __shfl(s4.y, DEGP, 64);
    float score = -INFINITY;
    if (lane < NE) {
        const float raw = (lane <= DEGP) ? sdp + s4.z : sdn + s4.w;
        score = (raw > 0.f) ? raw : LRELU_ALPHA * raw;
    }
    float m = score;
#pragma unroll
    for (int off = 32; off; off >>= 1) m = fmaxf(m, __shfl_xor(m, off, 64));
    const float ex = (lane < NE) ? __expf(score - m) : 0.f;
    float ssum = ex;
#pragma unroll
    for (int off = 32; off; off >>= 1) ssum += __shfl_xor(ssum, off, 64);
    const float att = ex / ssum;

    const unsigned short* whb = WhB + (size_t)h * U * 64;
    float acc = 0.f;
    for (int e = 0; e < NE; ++e) {
        const int   ce = __shfl(col, e, 64);
        const float ae = __shfl(att, e, 64);
        union { unsigned short s; __half hf; } w;
        w.s = whb[(size_t)(unsigned)ce * 64 + lane];
        acc = fmaf(ae, __half2float(w.hf), acc);
    }
    const int dim = ((lane & 15) >> 2) * 16 + (lane >> 4) * 4 + (lane & 3);
    out[(size_t)i * (H * 64) + h * 64 + dim] = fmaxf(acc, 0.f);
}

extern "C" void kernel_launch(void* const* d_in, const int* in_sizes, int n_in,
                              void* d_out, int out_size, void* d_ws, size_t ws_size,
                              hipStream_t stream) {
    const float* nf     = (const float*)d_in[0];
    const float* W      = (const float*)d_in[1];
    const float* a_pos  = (const float*)d_in[2];
    const float* a_neg  = (const float*)d_in[3];
    const float* ee     = (const float*)d_in[4];
    const float* et     = (const float*)d_in[5];
    const int* unique_nodes = (const int*)d_in[6];
    const int* pos_col  = (const int*)d_in[9];
    const int* neg_col  = (const int*)d_in[11];

    const int U    = in_sizes[6];
    const int N    = in_sizes[7];
    const int Epos = in_sizes[8];
    const int Eneg = in_sizes[10];
    const int H    = in_sizes[1] / (64 * 64);   // W is [H,64,64]
    const int DEGN = Eneg / N;                  // 16
    const int DEGP = Epos / N - 1;              // 16 (self edges appended)
    const int ET   = in_sizes[4] / 64;          // 32 edge types

    unsigned short* WhB = (unsigned short*)d_ws;
    const size_t whBytes = (((size_t)H * U * 64 * sizeof(unsigned short)) + 255) & ~(size_t)255;
    float4* sc4 = (float4*)((char*)d_ws + whBytes);
    const size_t scBytes = (((size_t)H * U * sizeof(float4)) + 255) & ~(size_t)255;
    unsigned short* Wt = (unsigned short*)((char*)d_ws + whBytes + scBytes);
    float* out = (float*)d_out;

    const int PT = H * 64 * 64 + H * 16 * 64 + ET * 64;
    prep_kernel<<<(PT + 255) / 256, 256, 0, stream>>>(W, a_pos, a_neg, ee, et, Wt,
                                                      out + (size_t)N * H * 64, H, ET);

    if (H == 4) {
        const long ublks = (U + 63) / 64;
        const long NBw = 8 * ((ublks + 1) / 2);
        wh_pinned_kernel<<<NBw, 256, 0, stream>>>(nf, Wt, unique_nodes, WhB, sc4, U);
    } else {
        wh_generic_kernel<<<(U + 15) / 16, 256, 0, stream>>>(nf, Wt, unique_nodes,
                                                             WhB, sc4, U, H);
    }

    if (DEGP == 16 && DEGN == 16 && H == 4 && (N % 8) == 0) {
        const long NB = (long)N;   // N*H/4 with H==4
        agg_pinned_kernel<<<NB, 256, 0, stream>>>(pos_col, neg_col, WhB, sc4, out, N, U, H);
    } else {
        agg_generic_kernel<<<((long)N * H + 3) / 4, 256, 0, stream>>>(
            pos_col, neg_col, WhB, sc4, out, N, U, DEGP, DEGN, H);
    }
}

// Round 10
// 49.478 us; speedup vs baseline: 1.7969x; 1.7969x over previous
//
#include <hip/hip_runtime.h>
#include <hip/hip_bf16.h>
#include <hip/hip_fp16.h>
#include <math.h>

#define LRELU_ALPHA 0.2f

typedef __attribute__((ext_vector_type(8))) short bf16x8;
typedef __attribute__((ext_vector_type(4))) float f32x4;

__device__ __forceinline__ unsigned short f2bf(float f) {
    union { float f; unsigned u; } v; v.f = f;
    unsigned r = v.u + 0x7fffu + ((v.u >> 16) & 1u);
    return (unsigned short)(r >> 16);
}
__device__ __forceinline__ unsigned cvtpk(float lo, float hi) {
    unsigned r;
    asm("v_cvt_pk_bf16_f32 %0, %1, %2" : "=v"(r) : "v"(lo), "v"(hi));
    return r;
}
__device__ __forceinline__ __half2 u2h2(unsigned u) {
    union { unsigned u; __half2 h; } x; x.u = u; return x.h;
}
__device__ __forceinline__ unsigned h22u(__half2 h) {
    union { __half2 h; unsigned u; } x; x.h = h; return x.u;
}

// ---------------- K0 prep: Wt + avB + edge_out --------------------------------------
// Wt[h][n][k] = bf16(W[h][k][n])            (H*64*64)
// avB[h*4+q][k] = bf16(sum_o W[h][k][o] * a_q[o]), a_q = {ap_dst, ap_src, an_dst, an_src}
// edge_out = ee @ et
__global__ void prep_kernel(const float* __restrict__ W,
                            const float* __restrict__ a_pos, const float* __restrict__ a_neg,
                            const float* __restrict__ ee, const float* __restrict__ et,
                            unsigned short* __restrict__ Wt, unsigned short* __restrict__ avB,
                            float* __restrict__ edge_out, int H, int ET) {
    const int HE = H * 4096, AV = H * 256;
    int t = blockIdx.x * blockDim.x + threadIdx.x;
    if (t < HE) {
        int k = t & 63, n = (t >> 6) & 63, h = t >> 12;
        Wt[((size_t)h * 64 + n) * 64 + k] = f2bf(W[(size_t)h * 4096 + k * 64 + n]);
    } else if (t < HE + AV) {
        int s = t - HE;
        int k = s & 63, q = (s >> 6) & 3, h = s >> 8;
        const float* a  = (q < 2 ? a_pos : a_neg) + (size_t)h * 128 + (q & 1) * 64;
        const float* wr = W + (size_t)h * 4096 + k * 64;
        float v = 0.f;
#pragma unroll
        for (int o = 0; o < 64; o += 4) {
            const float4 wv = *(const float4*)(wr + o);
            const float4 av = *(const float4*)(a + o);
            v = fmaf(wv.x, av.x, fmaf(wv.y, av.y, fmaf(wv.z, av.z, fmaf(wv.w, av.w, v))));
        }
        avB[((size_t)h * 4 + q) * 64 + k] = f2bf(v);
    } else {
        int s = t - HE - AV;
        if (s < ET * 64) {
            int e = s >> 6, o = s & 63;
            float acc = 0.f;
#pragma unroll
            for (int k = 0; k < 64; ++k)
                acc = fmaf(ee[e * 64 + k], et[k * 64 + o], acc);
            edge_out[s] = acc;
        }
    }
}

// ---------------- K1 (H==4): embed f32->f16 + 16-col score MFMA ---------------------
// Wave = 16 u's. Lane (grp,r): gathers nf row u0+r (k=grp*8 slices), stores f16 row,
// one swapped MFMA pair vs avB tile gives lane(grp=h,r): acc[j] = score q=j, head grp.
// sc_dst[u*4+h] = {pd,nd}; sc_src[u*4+h] = {ps,ns}.
__global__ __launch_bounds__(256) void score_cvt_kernel(
    const float* __restrict__ nf, const unsigned short* __restrict__ avB,
    const int* __restrict__ un, unsigned short* __restrict__ embed16,
    float2* __restrict__ sc_dst, float2* __restrict__ sc_src, int U)
{
    const int wave = threadIdx.x >> 6;
    const int lane = threadIdx.x & 63;
    const int grp  = lane >> 4;
    const int r    = lane & 15;
    const long u0  = (long)blockIdx.x * 64 + wave * 16;
    if (u0 >= U) return;
    const long u  = u0 + r;
    const long ur = (u < U) ? u : (long)(U - 1);

    const float* erow = nf + (size_t)un[ur] * 64 + grp * 8;
    const float4 e0 = *(const float4*)(erow);
    const float4 e1 = *(const float4*)(erow + 4);
    const float4 e2 = *(const float4*)(erow + 32);
    const float4 e3 = *(const float4*)(erow + 36);

    union { unsigned d[4]; bf16x8 v; } A0, A1;
    A0.d[0] = cvtpk(e0.x, e0.y); A0.d[1] = cvtpk(e0.z, e0.w);
    A0.d[2] = cvtpk(e1.x, e1.y); A0.d[3] = cvtpk(e1.z, e1.w);
    A1.d[0] = cvtpk(e2.x, e2.y); A1.d[1] = cvtpk(e2.z, e2.w);
    A1.d[2] = cvtpk(e3.x, e3.y); A1.d[3] = cvtpk(e3.z, e3.w);

    if (u < U) {   // f16 row store (in-order dims)
        union { __half2 h2[4]; uint4 v; } F0, F1;
        F0.h2[0] = __floats2half2_rn(e0.x, e0.y); F0.h2[1] = __floats2half2_rn(e0.z, e0.w);
        F0.h2[2] = __floats2half2_rn(e1.x, e1.y); F0.h2[3] = __floats2half2_rn(e1.z, e1.w);
        F1.h2[0] = __floats2half2_rn(e2.x, e2.y); F1.h2[1] = __floats2half2_rn(e2.z, e2.w);
        F1.h2[2] = __floats2half2_rn(e3.x, e3.y); F1.h2[3] = __floats2half2_rn(e3.z, e3.w);
        *(uint4*)(embed16 + (size_t)u * 64 + grp * 8)      = F0.v;
        *(uint4*)(embed16 + (size_t)u * 64 + 32 + grp * 8) = F1.v;
    }

    f32x4 acc = (f32x4)(0.f);
    const unsigned short* wp = avB + (size_t)r * 64 + grp * 8;
    bf16x8 b0 = *(const bf16x8*)wp;
    bf16x8 b1 = *(const bf16x8*)(wp + 32);
    acc = __builtin_amdgcn_mfma_f32_16x16x32_bf16(b0, A0.v, acc, 0, 0, 0);
    acc = __builtin_amdgcn_mfma_f32_16x16x32_bf16(b1, A1.v, acc, 0, 0, 0);

    if (u < U) {   // lane (grp=h, r): q = j
        sc_dst[(size_t)u * 4 + grp] = make_float2(acc[0], acc[2]);   // {pd, nd}
        sc_src[(size_t)u * 4 + grp] = make_float2(acc[1], acc[3]);   // {ps, ns}
    }
}

// ---------------- K2 (H==4, DEG 16/16): embed-space aggregation ---------------------
// One row i per wave. 33 edges; 4 heads served by ONE gather (cols head-independent).
// Lane mlo<32 owns dims {2mlo,2mlo+1}; halves split edges. 4 hfma2 per dword gathered.
__global__ __launch_bounds__(256) void agg4_kernel(
    const int* __restrict__ pos_col, const int* __restrict__ neg_col,
    const unsigned short* __restrict__ embed16,
    const float2* __restrict__ sc_dst, const float2* __restrict__ sc_src,
    unsigned short* __restrict__ aggb, int N, int U)
{
    constexpr int DP = 16, NE = 33, NEP = 34;
    __shared__ int  s_col[4][NEP];
    __shared__ uint4 s_att[4][NEP];

    const int wave = threadIdx.x >> 6;
    const int lane = threadIdx.x & 63;
    const int i = blockIdx.x * 4 + wave;
    if (i >= N) return;

    int col = 0;
    if (lane < DP)       col = pos_col[(size_t)i * DP + lane];
    else if (lane == DP) col = pos_col[(size_t)N * DP + i];          // self edge
    else if (lane < NE)  col = neg_col[(size_t)i * 16 + (lane - DP - 1)];

    // per-edge src scores {ps,ns} x4 heads (32 B), self-col dst scores broadcast
    const float4* ssv = (const float4*)sc_src;
    const float4 sA = ssv[2 * (size_t)(unsigned)col];
    const float4 sB = ssv[2 * (size_t)(unsigned)col + 1];
    const int u0s = __shfl(col, DP, 64);
    const float4* sdv = (const float4*)sc_dst;
    const float4 dA = sdv[2 * (size_t)(unsigned)u0s];      // {pd0,nd0,pd1,nd1}
    const float4 dB = sdv[2 * (size_t)(unsigned)u0s + 1];  // {pd2,nd2,pd3,nd3}

    const bool isp = (lane <= DP);
    float s0 = isp ? dA.x + sA.x : dA.y + sA.y;
    float s1 = isp ? dA.z + sA.z : dA.w + sA.w;
    float s2 = isp ? dB.x + sB.x : dB.y + sB.y;
    float s3 = isp ? dB.z + sB.z : dB.w + sB.w;
    s0 = (s0 > 0.f) ? s0 : LRELU_ALPHA * s0;
    s1 = (s1 > 0.f) ? s1 : LRELU_ALPHA * s1;
    s2 = (s2 > 0.f) ? s2 : LRELU_ALPHA * s2;
    s3 = (s3 > 0.f) ? s3 : LRELU_ALPHA * s3;
    if (lane >= NE) { s0 = s1 = s2 = s3 = -INFINITY; }

    float m0 = s0, m1 = s1, m2 = s2, m3 = s3;
#pragma unroll
    for (int off = 32; off; off >>= 1) {
        m0 = fmaxf(m0, __shfl_xor(m0, off, 64));
        m1 = fmaxf(m1, __shfl_xor(m1, off, 64));
        m2 = fmaxf(m2, __shfl_xor(m2, off, 64));
        m3 = fmaxf(m3, __shfl_xor(m3, off, 64));
    }
    const float x0 = (lane < NE) ? __expf(s0 - m0) : 0.f;
    const float x1 = (lane < NE) ? __expf(s1 - m1) : 0.f;
    const float x2 = (lane < NE) ? __expf(s2 - m2) : 0.f;
    const float x3 = (lane < NE) ? __expf(s3 - m3) : 0.f;
    float S0 = x0, S1 = x1, S2 = x2, S3 = x3;
#pragma unroll
    for (int off = 32; off; off >>= 1) {
        S0 += __shfl_xor(S0, off, 64);
        S1 += __shfl_xor(S1, off, 64);
        S2 += __shfl_xor(S2, off, 64);
        S3 += __shfl_xor(S3, off, 64);
    }
    const float a0f = __fdividef(x0, S0), a1f = __fdividef(x1, S1);
    const float a2f = __fdividef(x2, S2), a3f = __fdividef(x3, S3);

    if (lane < NEP) {   // lane 33 pad: col=0, att=0
        uint4 a4;
        a4.x = h22u(__float2half2_rn(a0f));
        a4.y = h22u(__float2half2_rn(a1f));
        a4.z = h22u(__float2half2_rn(a2f));
        a4.w = h22u(__float2half2_rn(a3f));
        s_col[wave][lane] = col;
        s_att[wave][lane] = a4;
    }
    // wave-private LDS slice; same-wave DS ordering, no barrier needed

    const int half = lane >> 5, mlo = lane & 31;
    const char* eb = (const char*)embed16 + (mlo << 2);
    __half2 ac0 = __float2half2_rn(0.f), ac1 = ac0, ac2 = ac0, ac3 = ac0;
#pragma unroll
    for (int t = 0; t < 17; ++t) {
        const int e = 2 * t + half;
        const int ce = s_col[wave][e];
        const uint4 a4 = s_att[wave][e];
        const unsigned v = *(const unsigned*)(eb + ((size_t)(unsigned)ce << 7));
        const __half2 vh = u2h2(v);
        ac0 = __hfma2(u2h2(a4.x), vh, ac0);
        ac1 = __hfma2(u2h2(a4.y), vh, ac1);
        ac2 = __hfma2(u2h2(a4.z), vh, ac2);
        ac3 = __hfma2(u2h2(a4.w), vh, ac3);
    }
    float2 f0 = __half22float2(ac0), f1 = __half22float2(ac1);
    float2 f2 = __half22float2(ac2), f3 = __half22float2(ac3);
    f0.x += __shfl_xor(f0.x, 32, 64); f0.y += __shfl_xor(f0.y, 32, 64);
    f1.x += __shfl_xor(f1.x, 32, 64); f1.y += __shfl_xor(f1.y, 32, 64);
    f2.x += __shfl_xor(f2.x, 32, 64); f2.y += __shfl_xor(f2.y, 32, 64);
    f3.x += __shfl_xor(f3.x, 32, 64); f3.y += __shfl_xor(f3.y, 32, 64);
    if (lane < 32) {
        unsigned* ap = (unsigned*)(aggb + (size_t)i * 256);   // [i][h][64] bf16
        ap[0 * 32 + mlo] = cvtpk(f0.x, f0.y);
        ap[1 * 32 + mlo] = cvtpk(f1.x, f1.y);
        ap[2 * 32 + mlo] = cvtpk(f2.x, f2.y);
        ap[3 * 32 + mlo] = cvtpk(f3.x, f3.y);
    }
}

// ---------------- K3: out[i][h] = relu(agg[i][h] @ W[h])  (any H) -------------------
__global__ __launch_bounds__(256) void out_gemm_kernel(
    const unsigned short* __restrict__ aggb, const unsigned short* __restrict__ Wt,
    float* __restrict__ out, int N, int H)
{
    const int wave = threadIdx.x >> 6;
    const int lane = threadIdx.x & 63;
    const int grp  = lane >> 4;
    const int r    = lane & 15;
    const long j = (long)blockIdx.x * 4 + wave;
    const int  h = (int)(j % H);
    const long i0 = (j / H) * 16;
    if (i0 >= N) return;
    const long i  = i0 + r;
    const long ir = (i < N) ? i : (long)(N - 1);

    const unsigned short* arow = aggb + ((size_t)ir * H + h) * 64 + grp * 8;
    bf16x8 a0 = *(const bf16x8*)arow;
    bf16x8 a1 = *(const bf16x8*)(arow + 32);

    f32x4 acc[4];
#pragma unroll
    for (int nt = 0; nt < 4; ++nt) {
        acc[nt] = (f32x4)(0.f);
        const unsigned short* wp = Wt + (((size_t)h * 64 + nt * 16 + r) * 64 + grp * 8);
        bf16x8 b0 = *(const bf16x8*)wp;
        bf16x8 b1 = *(const bf16x8*)(wp + 32);
        acc[nt] = __builtin_amdgcn_mfma_f32_16x16x32_bf16(b0, a0, acc[nt], 0, 0, 0);
        acc[nt] = __builtin_amdgcn_mfma_f32_16x16x32_bf16(b1, a1, acc[nt], 0, 0, 0);
    }
    if (i < N) {
        float* orow = out + ((size_t)i * H + h) * 64;
#pragma unroll
        for (int nt = 0; nt < 4; ++nt) {
            float4 o;
            o.x = fmaxf(acc[nt][0], 0.f); o.y = fmaxf(acc[nt][1], 0.f);
            o.z = fmaxf(acc[nt][2], 0.f); o.w = fmaxf(acc[nt][3], 0.f);
            *(float4*)(orow + nt * 16 + grp * 4) = o;
        }
    }
}

// ---------------- generic fallbacks (correctness-only, any shape) -------------------
__global__ void embed_cvt_generic(const float* __restrict__ nf, const int* __restrict__ un,
                                  unsigned short* __restrict__ embed16, int U) {
    long t = (long)blockIdx.x * blockDim.x + threadIdx.x;
    if (t >= (long)U * 64) return;
    union { __half h; unsigned short s; } c;
    c.h = __float2half_rn(nf[(size_t)un[t >> 6] * 64 + (t & 63)]);
    embed16[t] = c.s;
}
__global__ void score_generic(const unsigned short* __restrict__ embed16,
                              const unsigned short* __restrict__ avB,
                              float2* __restrict__ sc_dst, float2* __restrict__ sc_src,
                              int U, int H) {
    long t = (long)blockIdx.x * blockDim.x + threadIdx.x;
    if (t >= (long)U * H) return;
    const long u = t / H; const int h = (int)(t % H);
    float s[4];
    for (int q = 0; q < 4; ++q) {
        float acc = 0.f;
        for (int k = 0; k < 64; ++k) {
            union { unsigned short s; __half h; } w; w.s = embed16[u * 64 + k];
            union { unsigned u; float f; } b; b.u = ((unsigned)avB[((size_t)h * 4 + q) * 64 + k]) << 16;
            acc = fmaf(__half2float(w.h), b.f, acc);
        }
        s[q] = acc;
    }
    sc_dst[u * H + h] = make_float2(s[0], s[2]);
    sc_src[u * H + h] = make_float2(s[1], s[3]);
}
__global__ __launch_bounds__(256) void agg_generic(
    const int* __restrict__ pos_col, const int* __restrict__ neg_col,
    const unsigned short* __restrict__ embed16,
    const float2* __restrict__ sc_dst, const float2* __restrict__ sc_src,
    unsigned short* __restrict__ aggb, int N, int U, int DEGP, int DEGN, int H)
{
    const int wave = threadIdx.x >> 6;
    const int lane = threadIdx.x & 63;
    const long j = (long)blockIdx.x * 4 + wave;
    const int i = (int)(j % N);
    const int h = (int)(j / N);
    if (h >= H) return;
    const int NE = DEGP + 1 + DEGN;

    int col = 0;
    if (lane < DEGP)       col = pos_col[(size_t)i * DEGP + lane];
    else if (lane == DEGP) col = pos_col[(size_t)N * DEGP + i];
    else if (lane < NE)    col = neg_col[(size_t)i * DEGN + (lane - DEGP - 1)];
    const float2 ss = sc_src[(size_t)col * H + h];
    const int u0s = __shfl(col, DEGP, 64);
    const float2 sd = sc_dst[(size_t)u0s * H + h];
    float score = -INFINITY;
    if (lane < NE) {
        const float raw = (lane <= DEGP) ? sd.x + ss.x : sd.y + ss.y;
        score = (raw > 0.f) ? raw : LRELU_ALPHA * raw;
    }
    float m = score;
#pragma unroll
    for (int off = 32; off; off >>= 1) m = fmaxf(m, __shfl_xor(m, off, 64));
    const float ex = (lane < NE) ? __expf(score - m) : 0.f;
    float S = ex;
#pragma unroll
    for (int off = 32; off; off >>= 1) S += __shfl_xor(S, off, 64);
    const float att = __fdividef(ex, S);

    float acc = 0.f;
    for (int e = 0; e < NE; ++e) {
        const int   ce = __shfl(col, e, 64);
        const float ae = __shfl(att, e, 64);
        union { unsigned short s; __half h; } w; w.s = embed16[(size_t)(unsigned)ce * 64 + lane];
        acc = fmaf(ae, __half2float(w.h), acc);
    }
    aggb[((size_t)i * H + h) * 64 + lane] = f2bf(acc);
}

extern "C" void kernel_launch(void* const* d_in, const int* in_sizes, int n_in,
                              void* d_out, int out_size, void* d_ws, size_t ws_size,
                              hipStream_t stream) {
    const float* nf     = (const float*)d_in[0];
    const float* W      = (const float*)d_in[1];
    const float* a_pos  = (const float*)d_in[2];
    const float* a_neg  = (const float*)d_in[3];
    const float* ee     = (const float*)d_in[4];
    const float* et     = (const float*)d_in[5];
    const int* unique_nodes = (const int*)d_in[6];
    const int* pos_col  = (const int*)d_in[9];
    const int* neg_col  = (const int*)d_in[11];

    const int U    = in_sizes[6];
    const int N    = in_sizes[7];
    const int Epos = in_sizes[8];
    const int Eneg = in_sizes[10];
    const int H    = in_sizes[1] / (64 * 64);
    const int DEGN = Eneg / N;
    const int DEGP = Epos / N - 1;
    const int ET   = in_sizes[4] / 64;

    char* ws = (char*)d_ws;
    auto alloc = [&](size_t bytes) { char* p = ws; ws += (bytes + 255) & ~(size_t)255; return p; };
    unsigned short* embed16 = (unsigned short*)alloc((size_t)U * 64 * 2);
    float2*         sc_dst  = (float2*)alloc((size_t)U * H * 8);
    float2*         sc_src  = (float2*)alloc((size_t)U * H * 8);
    unsigned short* aggb    = (unsigned short*)alloc((size_t)N * H * 64 * 2);
    unsigned short* Wt      = (unsigned short*)alloc((size_t)H * 4096 * 2);
    unsigned short* avB     = (unsigned short*)alloc((size_t)H * 256 * 2);
    float* out = (float*)d_out;

    const int PT = H * 4096 + H * 256 + ET * 64;
    prep_kernel<<<(PT + 255) / 256, 256, 0, stream>>>(W, a_pos, a_neg, ee, et, Wt, avB,
                                                      out + (size_t)N * H * 64, H, ET);

    if (H == 4 && DEGP == 16 && DEGN == 16) {
        score_cvt_kernel<<<(U + 63) / 64, 256, 0, stream>>>(nf, avB, unique_nodes,
                                                            embed16, sc_dst, sc_src, U);
        agg4_kernel<<<(N + 3) / 4, 256, 0, stream>>>(pos_col, neg_col, embed16,
                                                     sc_dst, sc_src, aggb, N, U);
    } else {
        embed_cvt_generic<<<(int)(((long)U * 64 + 255) / 256), 256, 0, stream>>>(
            nf, unique_nodes, embed16, U);
        score_generic<<<(int)(((long)U * H + 255) / 256), 256, 0, stream>>>(
            embed16, avB, sc_dst, sc_src, U, H);
        agg_generic<<<(int)(((long)N * H + 3) / 4), 256, 0, stream>>>(
            pos_col, neg_col, embed16, sc_dst, sc_src, aggb, N, U, DEGP, DEGN, H);
    }

    const long tiles = ((long)N + 15) / 16;
    out_gemm_kernel<<<(int)((tiles * H + 3) / 4), 256, 0, stream>>>(aggb, Wt, out, N, H);
}

// Round 11
// 47.566 us; speedup vs baseline: 1.8691x; 1.0402x over previous
//
#include <hip/hip_runtime.h>
#include <hip/hip_bf16.h>
#include <hip/hip_fp16.h>
#include <math.h>

#define LRELU_ALPHA 0.2f

typedef __attribute__((ext_vector_type(8))) short bf16x8;
typedef __attribute__((ext_vector_type(4))) float f32x4;
typedef _Float16 f16x8 __attribute__((ext_vector_type(8)));

__device__ __forceinline__ unsigned short f2bf(float f) {
    union { float f; unsigned u; } v; v.f = f;
    unsigned r = v.u + 0x7fffu + ((v.u >> 16) & 1u);
    return (unsigned short)(r >> 16);
}
__device__ __forceinline__ unsigned short f2h(float f) {
    union { __half h; unsigned short s; } c; c.h = __float2half_rn(f); return c.s;
}
__device__ __forceinline__ unsigned cvtpk(float lo, float hi) {
    unsigned r;
    asm("v_cvt_pk_bf16_f32 %0, %1, %2" : "=v"(r) : "v"(lo), "v"(hi));
    return r;
}
__device__ __forceinline__ __half2 u2h2(unsigned u) {
    union { unsigned u; __half2 h; } x; x.u = u; return x.h;
}
__device__ __forceinline__ unsigned h22u(__half2 h) {
    union { __half2 h; unsigned u; } x; x.h = h; return x.u;
}

// ---------------- K0 prep: Wt(f16) + avB(bf16) + edge_out ---------------------------
__global__ void prep_kernel(const float* __restrict__ W,
                            const float* __restrict__ a_pos, const float* __restrict__ a_neg,
                            const float* __restrict__ ee, const float* __restrict__ et,
                            unsigned short* __restrict__ Wt, unsigned short* __restrict__ avB,
                            float* __restrict__ edge_out, int H, int ET) {
    const int HE = H * 4096, AV = H * 256;
    int t = blockIdx.x * blockDim.x + threadIdx.x;
    if (t < HE) {
        int k = t & 63, n = (t >> 6) & 63, h = t >> 12;
        Wt[((size_t)h * 64 + n) * 64 + k] = f2h(W[(size_t)h * 4096 + k * 64 + n]);
    } else if (t < HE + AV) {
        int s = t - HE;
        int k = s & 63, q = (s >> 6) & 3, h = s >> 8;
        const float* a  = (q < 2 ? a_pos : a_neg) + (size_t)h * 128 + (q & 1) * 64;
        const float* wr = W + (size_t)h * 4096 + k * 64;
        float v = 0.f;
#pragma unroll
        for (int o = 0; o < 64; o += 4) {
            const float4 wv = *(const float4*)(wr + o);
            const float4 av = *(const float4*)(a + o);
            v = fmaf(wv.x, av.x, fmaf(wv.y, av.y, fmaf(wv.z, av.z, fmaf(wv.w, av.w, v))));
        }
        avB[((size_t)h * 4 + q) * 64 + k] = f2bf(v);
    } else {
        int s = t - HE - AV;
        if (s < ET * 64) {
            int e = s >> 6, o = s & 63;
            float acc = 0.f;
#pragma unroll
            for (int k = 0; k < 64; ++k)
                acc = fmaf(ee[e * 64 + k], et[k * 64 + o], acc);
            edge_out[s] = acc;
        }
    }
}

// ---------------- K1 (H==4): embed f32->f16 + 16-col score MFMA ---------------------
__global__ __launch_bounds__(256) void score_cvt_kernel(
    const float* __restrict__ nf, const unsigned short* __restrict__ avB,
    const int* __restrict__ un, unsigned short* __restrict__ embed16,
    float2* __restrict__ sc_dst, float2* __restrict__ sc_src, int U)
{
    const int wave = threadIdx.x >> 6;
    const int lane = threadIdx.x & 63;
    const int grp  = lane >> 4;
    const int r    = lane & 15;
    const long u0  = (long)blockIdx.x * 64 + wave * 16;
    if (u0 >= U) return;
    const long u  = u0 + r;
    const long ur = (u < U) ? u : (long)(U - 1);

    const float* erow = nf + (size_t)un[ur] * 64 + grp * 8;
    const float4 e0 = *(const float4*)(erow);
    const float4 e1 = *(const float4*)(erow + 4);
    const float4 e2 = *(const float4*)(erow + 32);
    const float4 e3 = *(const float4*)(erow + 36);

    union { unsigned d[4]; bf16x8 v; } A0, A1;
    A0.d[0] = cvtpk(e0.x, e0.y); A0.d[1] = cvtpk(e0.z, e0.w);
    A0.d[2] = cvtpk(e1.x, e1.y); A0.d[3] = cvtpk(e1.z, e1.w);
    A1.d[0] = cvtpk(e2.x, e2.y); A1.d[1] = cvtpk(e2.z, e2.w);
    A1.d[2] = cvtpk(e3.x, e3.y); A1.d[3] = cvtpk(e3.z, e3.w);

    if (u < U) {
        union { __half2 h2[4]; uint4 v; } F0, F1;
        F0.h2[0] = __floats2half2_rn(e0.x, e0.y); F0.h2[1] = __floats2half2_rn(e0.z, e0.w);
        F0.h2[2] = __floats2half2_rn(e1.x, e1.y); F0.h2[3] = __floats2half2_rn(e1.z, e1.w);
        F1.h2[0] = __floats2half2_rn(e2.x, e2.y); F1.h2[1] = __floats2half2_rn(e2.z, e2.w);
        F1.h2[2] = __floats2half2_rn(e3.x, e3.y); F1.h2[3] = __floats2half2_rn(e3.z, e3.w);
        *(uint4*)(embed16 + (size_t)u * 64 + grp * 8)      = F0.v;
        *(uint4*)(embed16 + (size_t)u * 64 + 32 + grp * 8) = F1.v;
    }

    f32x4 acc = (f32x4)(0.f);
    const unsigned short* wp = avB + (size_t)r * 64 + grp * 8;
    bf16x8 b0 = *(const bf16x8*)wp;
    bf16x8 b1 = *(const bf16x8*)(wp + 32);
    acc = __builtin_amdgcn_mfma_f32_16x16x32_bf16(b0, A0.v, acc, 0, 0, 0);
    acc = __builtin_amdgcn_mfma_f32_16x16x32_bf16(b1, A1.v, acc, 0, 0, 0);

    if (u < U) {
        sc_dst[(size_t)u * 4 + grp] = make_float2(acc[0], acc[2]);   // {pd, nd}
        sc_src[(size_t)u * 4 + grp] = make_float2(acc[1], acc[3]);   // {ps, ns}
    }
}

// ---------------- K2 fused (H==4, DEG 16/16, N%16==0): agg + out GEMM ---------------
// Block = 512 thr (8 waves) = 16 rows. Phase 1: wave w aggregates rows 2w, 2w+1
// (interleaved for MLP): 9 gather iters of uint2 (4 edge-subgroups x 16 chunks),
// softmax without max-subtract, result f16 rows -> LDS. Phase 2: waves 0-3 = head h:
// 16x64 @ 64x64 f16 MFMA from LDS, relu, store.
__global__ __launch_bounds__(512) void aggemm_kernel(
    const int* __restrict__ pos_col, const int* __restrict__ neg_col,
    const unsigned short* __restrict__ embed16,
    const float2* __restrict__ sc_dst, const float2* __restrict__ sc_src,
    const unsigned short* __restrict__ Wt,
    float* __restrict__ out, int N, int U)
{
    constexpr int DP = 16, NE = 33, NEP = 36;
    __shared__ int   s_col[8][2][NEP];
    __shared__ uint4 s_att[8][2][NEP];
    __shared__ __align__(16) unsigned short s_agg[16][256];  // [row][h*64+dim] f16

    const int wave = threadIdx.x >> 6;
    const int lane = threadIdx.x & 63;
    const int iA = blockIdx.x * 16 + wave * 2;
    const int iB = iA + 1;

    // ---- cols for both rows
    int colA = 0, colB = 0;
    if (lane < DP)       { colA = pos_col[(size_t)iA * DP + lane];
                           colB = pos_col[(size_t)iB * DP + lane]; }
    else if (lane == DP) { colA = pos_col[(size_t)N * DP + iA];
                           colB = pos_col[(size_t)N * DP + iB]; }
    else if (lane < NE)  { colA = neg_col[(size_t)iA * 16 + (lane - DP - 1)];
                           colB = neg_col[(size_t)iB * 16 + (lane - DP - 1)]; }

    // ---- scores (src per lane, dst broadcast from self-edge lane)
    const float4* ssv = (const float4*)sc_src;
    const float4 sA0 = ssv[2 * (size_t)(unsigned)colA];
    const float4 sA1 = ssv[2 * (size_t)(unsigned)colA + 1];
    const float4 sB0 = ssv[2 * (size_t)(unsigned)colB];
    const float4 sB1 = ssv[2 * (size_t)(unsigned)colB + 1];
    const int uA = __shfl(colA, DP, 64), uB = __shfl(colB, DP, 64);
    const float4* sdv = (const float4*)sc_dst;
    const float4 dA0 = sdv[2 * (size_t)(unsigned)uA];
    const float4 dA1 = sdv[2 * (size_t)(unsigned)uA + 1];
    const float4 dB0 = sdv[2 * (size_t)(unsigned)uB];
    const float4 dB1 = sdv[2 * (size_t)(unsigned)uB + 1];

    const bool isp = (lane <= DP);
    float a_s0 = isp ? dA0.x + sA0.x : dA0.y + sA0.y;
    float a_s1 = isp ? dA0.z + sA0.z : dA0.w + sA0.w;
    float a_s2 = isp ? dA1.x + sA1.x : dA1.y + sA1.y;
    float a_s3 = isp ? dA1.z + sA1.z : dA1.w + sA1.w;
    float b_s0 = isp ? dB0.x + sB0.x : dB0.y + sB0.y;
    float b_s1 = isp ? dB0.z + sB0.z : dB0.w + sB0.w;
    float b_s2 = isp ? dB1.x + sB1.x : dB1.y + sB1.y;
    float b_s3 = isp ? dB1.z + sB1.z : dB1.w + sB1.w;
    a_s0 = (a_s0 > 0.f) ? a_s0 : LRELU_ALPHA * a_s0;
    a_s1 = (a_s1 > 0.f) ? a_s1 : LRELU_ALPHA * a_s1;
    a_s2 = (a_s2 > 0.f) ? a_s2 : LRELU_ALPHA * a_s2;
    a_s3 = (a_s3 > 0.f) ? a_s3 : LRELU_ALPHA * a_s3;
    b_s0 = (b_s0 > 0.f) ? b_s0 : LRELU_ALPHA * b_s0;
    b_s1 = (b_s1 > 0.f) ? b_s1 : LRELU_ALPHA * b_s1;
    b_s2 = (b_s2 > 0.f) ? b_s2 : LRELU_ALPHA * b_s2;
    b_s3 = (b_s3 > 0.f) ? b_s3 : LRELU_ALPHA * b_s3;

    // exp WITHOUT max-subtract (scores are O(1); f32 exp cannot overflow here)
    const bool act = (lane < NE);
    float ax0 = act ? __expf(a_s0) : 0.f, ax1 = act ? __expf(a_s1) : 0.f;
    float ax2 = act ? __expf(a_s2) : 0.f, ax3 = act ? __expf(a_s3) : 0.f;
    float bx0 = act ? __expf(b_s0) : 0.f, bx1 = act ? __expf(b_s1) : 0.f;
    float bx2 = act ? __expf(b_s2) : 0.f, bx3 = act ? __expf(b_s3) : 0.f;
    float aS0 = ax0, aS1 = ax1, aS2 = ax2, aS3 = ax3;
    float bS0 = bx0, bS1 = bx1, bS2 = bx2, bS3 = bx3;
#pragma unroll
    for (int off = 32; off; off >>= 1) {
        aS0 += __shfl_xor(aS0, off, 64); aS1 += __shfl_xor(aS1, off, 64);
        aS2 += __shfl_xor(aS2, off, 64); aS3 += __shfl_xor(aS3, off, 64);
        bS0 += __shfl_xor(bS0, off, 64); bS1 += __shfl_xor(bS1, off, 64);
        bS2 += __shfl_xor(bS2, off, 64); bS3 += __shfl_xor(bS3, off, 64);
    }
    if (lane < NEP) {
        uint4 tA, tB;
        tA.x = h22u(__float2half2_rn(__fdividef(ax0, aS0)));
        tA.y = h22u(__float2half2_rn(__fdividef(ax1, aS1)));
        tA.z = h22u(__float2half2_rn(__fdividef(ax2, aS2)));
        tA.w = h22u(__float2half2_rn(__fdividef(ax3, aS3)));
        tB.x = h22u(__float2half2_rn(__fdividef(bx0, bS0)));
        tB.y = h22u(__float2half2_rn(__fdividef(bx1, bS1)));
        tB.z = h22u(__float2half2_rn(__fdividef(bx2, bS2)));
        tB.w = h22u(__float2half2_rn(__fdividef(bx3, bS3)));
        s_col[wave][0][lane] = colA;  s_att[wave][0][lane] = tA;   // pads: col=0, att=0
        s_col[wave][1][lane] = colB;  s_att[wave][1][lane] = tB;
    }
    // wave-private LDS slice: same-wave ordering, no barrier needed before the MAC loop

    // ---- MAC: 9 iters x 2 rows; lane = (sub = edge subgroup, c = uint2 dim-chunk)
    const int sub = lane >> 4;
    const int c   = lane & 15;
    const char* eb = (const char*)embed16 + (c << 3);
    __half2 accA[4][2], accB[4][2];
#pragma unroll
    for (int h = 0; h < 4; ++h)
        for (int d = 0; d < 2; ++d) {
            accA[h][d] = __float2half2_rn(0.f);
            accB[h][d] = __float2half2_rn(0.f);
        }
#pragma unroll
    for (int t = 0; t < 9; ++t) {
        const int   e  = 4 * t + sub;
        const int   cA = s_col[wave][0][e];
        const int   cB = s_col[wave][1][e];
        const uint2 vA = *(const uint2*)(eb + ((size_t)(unsigned)cA << 7));
        const uint2 vB = *(const uint2*)(eb + ((size_t)(unsigned)cB << 7));
        const uint4 tA = s_att[wave][0][e];
        const uint4 tB = s_att[wave][1][e];
        const __half2 vA0 = u2h2(vA.x), vA1 = u2h2(vA.y);
        const __half2 vB0 = u2h2(vB.x), vB1 = u2h2(vB.y);
        accA[0][0] = __hfma2(u2h2(tA.x), vA0, accA[0][0]);
        accA[0][1] = __hfma2(u2h2(tA.x), vA1, accA[0][1]);
        accA[1][0] = __hfma2(u2h2(tA.y), vA0, accA[1][0]);
        accA[1][1] = __hfma2(u2h2(tA.y), vA1, accA[1][1]);
        accA[2][0] = __hfma2(u2h2(tA.z), vA0, accA[2][0]);
        accA[2][1] = __hfma2(u2h2(tA.z), vA1, accA[2][1]);
        accA[3][0] = __hfma2(u2h2(tA.w), vA0, accA[3][0]);
        accA[3][1] = __hfma2(u2h2(tA.w), vA1, accA[3][1]);
        accB[0][0] = __hfma2(u2h2(tB.x), vB0, accB[0][0]);
        accB[0][1] = __hfma2(u2h2(tB.x), vB1, accB[0][1]);
        accB[1][0] = __hfma2(u2h2(tB.y), vB0, accB[1][0]);
        accB[1][1] = __hfma2(u2h2(tB.y), vB1, accB[1][1]);
        accB[2][0] = __hfma2(u2h2(tB.z), vB0, accB[2][0]);
        accB[2][1] = __hfma2(u2h2(tB.z), vB1, accB[2][1]);
        accB[3][0] = __hfma2(u2h2(tB.w), vB0, accB[3][0]);
        accB[3][1] = __hfma2(u2h2(tB.w), vB1, accB[3][1]);
    }
    // reduce across the 4 edge subgroups (lanes differing in bits 4,5)
#pragma unroll
    for (int h = 0; h < 4; ++h)
#pragma unroll
        for (int d = 0; d < 2; ++d) {
            unsigned ua = h22u(accA[h][d]);
            ua = h22u(__hadd2(u2h2(ua), u2h2(__shfl_xor((int)ua, 16, 64))));
            ua = h22u(__hadd2(u2h2(ua), u2h2(__shfl_xor((int)ua, 32, 64))));
            accA[h][d] = u2h2(ua);
            unsigned ub = h22u(accB[h][d]);
            ub = h22u(__hadd2(u2h2(ub), u2h2(__shfl_xor((int)ub, 16, 64))));
            ub = h22u(__hadd2(u2h2(ub), u2h2(__shfl_xor((int)ub, 32, 64))));
            accB[h][d] = u2h2(ub);
        }
    if (sub == 0) {   // lanes 0-15: write f16 agg rows (dims 4c..4c+3 per head)
#pragma unroll
        for (int h = 0; h < 4; ++h) {
            uint2 wA, wB;
            wA.x = h22u(accA[h][0]); wA.y = h22u(accA[h][1]);
            wB.x = h22u(accB[h][0]); wB.y = h22u(accB[h][1]);
            *(uint2*)((char*)&s_agg[wave * 2][h * 64] + c * 8)     = wA;
            *(uint2*)((char*)&s_agg[wave * 2 + 1][h * 64] + c * 8) = wB;
        }
    }
    __syncthreads();

    // ---- phase 2: waves 0-3 = head h; 16 rows x 64 dims f16 MFMA, relu, store
    if (wave < 4) {
        const int h   = wave;
        const int grp = lane >> 4;
        const int r   = lane & 15;
        const f16x8 a0 = *(const f16x8*)((const char*)&s_agg[r][h * 64] + grp * 16);
        const f16x8 a1 = *(const f16x8*)((const char*)&s_agg[r][h * 64 + 32] + grp * 16);
        f32x4 acc[4];
#pragma unroll
        for (int nt = 0; nt < 4; ++nt) {
            acc[nt] = (f32x4)(0.f);
            const unsigned short* wp = Wt + (((size_t)h * 64 + nt * 16 + r) * 64 + grp * 8);
            const f16x8 b0 = *(const f16x8*)wp;
            const f16x8 b1 = *(const f16x8*)(wp + 32);
            acc[nt] = __builtin_amdgcn_mfma_f32_16x16x32_f16(b0, a0, acc[nt], 0, 0, 0);
            acc[nt] = __builtin_amdgcn_mfma_f32_16x16x32_f16(b1, a1, acc[nt], 0, 0, 0);
        }
        float* orow = out + ((size_t)(blockIdx.x * 16 + r) * 4 + h) * 64;
#pragma unroll
        for (int nt = 0; nt < 4; ++nt) {
            float4 o;
            o.x = fmaxf(acc[nt][0], 0.f); o.y = fmaxf(acc[nt][1], 0.f);
            o.z = fmaxf(acc[nt][2], 0.f); o.w = fmaxf(acc[nt][3], 0.f);
            *(float4*)(orow + nt * 16 + grp * 4) = o;
        }
    }
}

// ---------------- generic fallbacks (correctness-only, any shape) -------------------
__global__ void embed_cvt_generic(const float* __restrict__ nf, const int* __restrict__ un,
                                  unsigned short* __restrict__ embed16, int U) {
    long t = (long)blockIdx.x * blockDim.x + threadIdx.x;
    if (t >= (long)U * 64) return;
    embed16[t] = f2h(nf[(size_t)un[t >> 6] * 64 + (t & 63)]);
}
__global__ void score_generic(const unsigned short* __restrict__ embed16,
                              const unsigned short* __restrict__ avB,
                              float2* __restrict__ sc_dst, float2* __restrict__ sc_src,
                              int U, int H) {
    long t = (long)blockIdx.x * blockDim.x + threadIdx.x;
    if (t >= (long)U * H) return;
    const long u = t / H; const int h = (int)(t % H);
    float s[4];
    for (int q = 0; q < 4; ++q) {
        float acc = 0.f;
        for (int k = 0; k < 64; ++k) {
            union { unsigned short s; __half h; } w; w.s = embed16[u * 64 + k];
            union { unsigned u; float f; } b; b.u = ((unsigned)avB[((size_t)h * 4 + q) * 64 + k]) << 16;
            acc = fmaf(__half2float(w.h), b.f, acc);
        }
        s[q] = acc;
    }
    sc_dst[u * H + h] = make_float2(s[0], s[2]);
    sc_src[u * H + h] = make_float2(s[1], s[3]);
}
__global__ __launch_bounds__(256) void agg_generic(
    const int* __restrict__ pos_col, const int* __restrict__ neg_col,
    const unsigned short* __restrict__ embed16,
    const float2* __restrict__ sc_dst, const float2* __restrict__ sc_src,
    unsigned short* __restrict__ aggb, int N, int U, int DEGP, int DEGN, int H)
{
    const int wave = threadIdx.x >> 6;
    const int lane = threadIdx.x & 63;
    const long j = (long)blockIdx.x * 4 + wave;
    const int i = (int)(j % N);
    const int h = (int)(j / N);
    if (h >= H) return;
    const int NE = DEGP + 1 + DEGN;

    int col = 0;
    if (lane < DEGP)       col = pos_col[(size_t)i * DEGP + lane];
    else if (lane == DEGP) col = pos_col[(size_t)N * DEGP + i];
    else if (lane < NE)    col = neg_col[(size_t)i * DEGN + (lane - DEGP - 1)];
    const float2 ss = sc_src[(size_t)col * H + h];
    const int u0s = __shfl(col, DEGP, 64);
    const float2 sd = sc_dst[(size_t)u0s * H + h];
    float score = -INFINITY;
    if (lane < NE) {
        const float raw = (lane <= DEGP) ? sd.x + ss.x : sd.y + ss.y;
        score = (raw > 0.f) ? raw : LRELU_ALPHA * raw;
    }
    float m = score;
#pragma unroll
    for (int off = 32; off; off >>= 1) m = fmaxf(m, __shfl_xor(m, off, 64));
    const float ex = (lane < NE) ? __expf(score - m) : 0.f;
    float S = ex;
#pragma unroll
    for (int off = 32; off; off >>= 1) S += __shfl_xor(S, off, 64);
    const float att = __fdividef(ex, S);

    float acc = 0.f;
    for (int e = 0; e < NE; ++e) {
        const int   ce = __shfl(col, e, 64);
        const float ae = __shfl(att, e, 64);
        union { unsigned short s; __half h; } w; w.s = embed16[(size_t)(unsigned)ce * 64 + lane];
        acc = fmaf(ae, __half2float(w.h), acc);
    }
    aggb[((size_t)i * H + h) * 64 + lane] = f2h(acc);
}
__global__ __launch_bounds__(256) void out_gemm_generic(
    const unsigned short* __restrict__ aggb, const unsigned short* __restrict__ Wt,
    float* __restrict__ out, int N, int H)
{
    const int wave = threadIdx.x >> 6;
    const int lane = threadIdx.x & 63;
    const int grp  = lane >> 4;
    const int r    = lane & 15;
    const long j = (long)blockIdx.x * 4 + wave;
    const int  h = (int)(j % H);
    const long i0 = (j / H) * 16;
    if (i0 >= N) return;
    const long i  = i0 + r;
    const long ir = (i < N) ? i : (long)(N - 1);

    const unsigned short* arow = aggb + ((size_t)ir * H + h) * 64 + grp * 8;
    const f16x8 a0 = *(const f16x8*)arow;
    const f16x8 a1 = *(const f16x8*)(arow + 32);
    f32x4 acc[4];
#pragma unroll
    for (int nt = 0; nt < 4; ++nt) {
        acc[nt] = (f32x4)(0.f);
        const unsigned short* wp = Wt + (((size_t)h * 64 + nt * 16 + r) * 64 + grp * 8);
        const f16x8 b0 = *(const f16x8*)wp;
        const f16x8 b1 = *(const f16x8*)(wp + 32);
        acc[nt] = __builtin_amdgcn_mfma_f32_16x16x32_f16(b0, a0, acc[nt], 0, 0, 0);
        acc[nt] = __builtin_amdgcn_mfma_f32_16x16x32_f16(b1, a1, acc[nt], 0, 0, 0);
    }
    if (i < N) {
        float* orow = out + ((size_t)i * H + h) * 64;
#pragma unroll
        for (int nt = 0; nt < 4; ++nt) {
            float4 o;
            o.x = fmaxf(acc[nt][0], 0.f); o.y = fmaxf(acc[nt][1], 0.f);
            o.z = fmaxf(acc[nt][2], 0.f); o.w = fmaxf(acc[nt][3], 0.f);
            *(float4*)(orow + nt * 16 + grp * 4) = o;
        }
    }
}

extern "C" void kernel_launch(void* const* d_in, const int* in_sizes, int n_in,
                              void* d_out, int out_size, void* d_ws, size_t ws_size,
                              hipStream_t stream) {
    const float* nf     = (const float*)d_in[0];
    const float* W      = (const float*)d_in[1];
    const float* a_pos  = (const float*)d_in[2];
    const float* a_neg  = (const float*)d_in[3];
    const float* ee     = (const float*)d_in[4];
    const float* et     = (const float*)d_in[5];
    const int* unique_nodes = (const int*)d_in[6];
    const int* pos_col  = (const int*)d_in[9];
    const int* neg_col  = (const int*)d_in[11];

    const int U    = in_sizes[6];
    const int N    = in_sizes[7];
    const int Epos = in_sizes[8];
    const int Eneg = in_sizes[10];
    const int H    = in_sizes[1] / (64 * 64);
    const int DEGN = Eneg / N;
    const int DEGP = Epos / N - 1;
    const int ET   = in_sizes[4] / 64;

    char* ws = (char*)d_ws;
    auto alloc = [&](size_t bytes) { char* p = ws; ws += (bytes + 255) & ~(size_t)255; return p; };
    unsigned short* embed16 = (unsigned short*)alloc((size_t)U * 64 * 2);
    float2*         sc_dst  = (float2*)alloc((size_t)U * H * 8);
    float2*         sc_src  = (float2*)alloc((size_t)U * H * 8);
    unsigned short* aggb    = (unsigned short*)alloc((size_t)N * H * 64 * 2);
    unsigned short* Wt      = (unsigned short*)alloc((size_t)H * 4096 * 2);
    unsigned short* avB     = (unsigned short*)alloc((size_t)H * 256 * 2);
    float* out = (float*)d_out;

    const int PT = H * 4096 + H * 256 + ET * 64;
    prep_kernel<<<(PT + 255) / 256, 256, 0, stream>>>(W, a_pos, a_neg, ee, et, Wt, avB,
                                                      out + (size_t)N * H * 64, H, ET);

    if (H == 4 && DEGP == 16 && DEGN == 16 && (N % 16) == 0) {
        score_cvt_kernel<<<(U + 63) / 64, 256, 0, stream>>>(nf, avB, unique_nodes,
                                                            embed16, sc_dst, sc_src, U);
        aggemm_kernel<<<N / 16, 512, 0, stream>>>(pos_col, neg_col, embed16,
                                                  sc_dst, sc_src, Wt, out, N, U);
    } else {
        embed_cvt_generic<<<(int)(((long)U * 64 + 255) / 256), 256, 0, stream>>>(
            nf, unique_nodes, embed16, U);
        score_generic<<<(int)(((long)U * H + 255) / 256), 256, 0, stream>>>(
            embed16, avB, sc_dst, sc_src, U, H);
        agg_generic<<<(int)(((long)N * H + 3) / 4), 256, 0, stream>>>(
            pos_col, neg_col, embed16, sc_dst, sc_src, aggb, N, U, DEGP, DEGN, H);
        const long tiles = ((long)N + 15) / 16;
        out_gemm_generic<<<(int)((tiles * H + 3) / 4), 256, 0, stream>>>(aggb, Wt, out, N, H);
    }
}